// Round 7
// baseline (285.212 us; speedup 1.0000x reference)
//
#include <hip/hip_runtime.h>
#include <math.h>

// Problem constants
#define NB   64
#define TT   2048
// Tail-window truncation: output = x[:, 2047]; the only temporal coupling is
// the LIF membrane (decay 0.5/step + hard reset). v(T0)=0 direct error at
// 2047 is 0.5^63; validated in prior rounds (TW=192 matched full scan).
#define TW   64
#define T0   (TT - TW)     // 1984
#define NR   (NB * TW)     // 4096 active rows

typedef float v2f __attribute__((ext_vector_type(2)));

__device__ __forceinline__ float gelu_exact(float x) {
    return 0.5f * x * (1.0f + erff(x * 0.7071067811865476f));
}
__device__ __forceinline__ unsigned long long rfl64(unsigned long long x) {
    unsigned lo = __builtin_amdgcn_readfirstlane((unsigned)x);
    unsigned hi = __builtin_amdgcn_readfirstlane((unsigned)(x >> 32));
    return ((unsigned long long)hi << 32) | lo;
}

// LDS float offsets (67.5 KB)
#define WB0_O  0        // [32][256] fc1-W quarter buffer 0 (32 KB)
#define WB1_O  8192     // quarter buffer 1; proj G[64][64] aliases here
#define V1_O   16384    // LIF1 v-state handoff (256 f)
#define V2_O   16640    // LIF2 v-state handoff (128 f)
#define MSK_O  16768    // spike masks: [8 waves][8 t][4] u64 = 512 f
#define LB_TOT 17280

// One block per batch, 64 x 1024 threads (16 waves), wave-specialized:
//   waves 0-7  = COMPUTE: 8 rows each (t = 8w..8w+7) in every phase.
//                W-LDS read traffic halves vs 16x4 (reads scale with waves).
//   waves 8-15 = STAGING: run the W1 quarter pipeline (global->reg ahead,
//                reg->LDS at the barrier) so HBM/L2 latency never touches
//                the compute waves. Same 4-barrier schedule as round 6.
// X lives in per-layer GLOBAL regions (L2-resident, 32KB/block/layer), read
// in the K-loop via wave-uniform s_load (scalar pipe — zero LDS issues;
// regions are written once then scalar-read once, so the scalar cache is
// always cold for them = coherent). LIF chains are 8-stage flag chains;
// spike masks pass through wave-private LDS + readfirstlane. All
// accumulation orders (k-order, a0+a1+a2+a3 + xor-tree LN, d-ascending
// sparse fc2 with exact-zero adds) are unchanged from rounds 2-6.
__global__ void __launch_bounds__(1024, 4) fused_kernel(
    const float* __restrict__ hist,
    const float* __restrict__ pw1, const float* __restrict__ pb1,
    const float* __restrict__ pw2, const float* __restrict__ pb2,
    const float* __restrict__ fc1w, const float* __restrict__ fc1b,
    const float* __restrict__ n1g,  const float* __restrict__ n1b,
    const float* __restrict__ fc2w, const float* __restrict__ fc2b,
    const float* __restrict__ n2g,  const float* __restrict__ n2b,
    const float* __restrict__ XbR, float* __restrict__ XbW,
    float* __restrict__ out)
{
    __shared__ __align__(16) float LB[LB_TOT];
    __shared__ int FLG[2];
    unsigned long long* MSK = (unsigned long long*)&LB[MSK_O];
    const int tid = threadIdx.x, wave = tid >> 6, lane = tid & 63;
    const int b = blockIdx.x;
    const int ht = tid & 511;            // helper-local index (waves 8-15)
    const int row0 = (wave & 7) * 8;     // compute-wave row base (8 rows)

    if (tid == 0) { FLG[0] = 0; FLG[1] = 0; }

    float4 ra, rb, rc, rd;   // staging regs: 64B/thread = one 32KB quarter
#define LOADQ(src) { const float4* p_ = (const float4*)(src); \
                     ra = p_[ht]; rb = p_[ht+512]; rc = p_[ht+1024]; rd = p_[ht+1536]; }
#define WRITEQ(off) { float4* q_ = (float4*)&LB[off]; \
                      q_[ht] = ra; q_[ht+512] = rb; q_[ht+1024] = rc; q_[ht+1536] = rd; }
#define CONSUME(WOFF, KQ) \
    { \
        _Pragma("unroll 2") \
        for (int k4 = 0; k4 < 8; ++k4) { \
            float4 xr[8]; \
            _Pragma("unroll") \
            for (int r = 0; r < 8; ++r) \
                xr[r] = *(const float4*)(x0 + r*128 + (KQ) + k4*4);  /* s_load */ \
            _Pragma("unroll") \
            for (int kk = 0; kk < 4; ++kk) { \
                float4 wv = ((const float4*)&LB[(WOFF) + (k4*4+kk)*256])[lane]; \
                v2f wA, wB; wA.x = wv.x; wA.y = wv.y; wB.x = wv.z; wB.y = wv.w; \
                _Pragma("unroll") \
                for (int r = 0; r < 8; ++r) { \
                    float xv = ((const float*)&xr[r])[kk]; \
                    accA[r] += wA * xv; \
                    accB[r] += wB * xv; \
                } \
            } \
        } \
    }

    if (wave >= 8) LOADQ(fc1w);                // s0(L0) in flight (helpers)

    // ---------------- proj1: all 16 waves, 4 rows each -> G in WB1 ----------
    {
        const int pr0 = wave * 4;
        const float* hb = hist + ((size_t)b * TT + T0) * 4;
        float w0 = pw1[lane], w1 = pw1[64+lane], w2 = pw1[128+lane], w3 = pw1[192+lane];
        float bb = pb1[lane];
        #pragma unroll
        for (int r = 0; r < 4; ++r) {
            int t = pr0 + r;
            float4 h = *(const float4*)(hb + t*4);          // wave-uniform
            LB[WB1_O + t*64 + lane] = gelu_exact(bb + h.x*w0 + h.y*w1 + h.z*w2 + h.w*w3);
        }
    }
    if (wave >= 8) { WRITEQ(WB0_O); LOADQ(fc1w + 8192); }   // s0->B0; s1 in flight
    // ---------------- proj2: all 16 waves, own 4 G rows -> X0 (global) ------
    {
        const int pr0 = wave * 4;
        float* X0 = XbW + (size_t)b * TW * 128;
        float2 bv = ((const float2*)pb2)[lane];
        v2f acc[4];
        #pragma unroll
        for (int r = 0; r < 4; ++r) { acc[r].x = 0.f; acc[r].y = 0.f; }
        #pragma unroll 2
        for (int k4 = 0; k4 < 16; ++k4) {
            float4 xr[4];
            #pragma unroll
            for (int r = 0; r < 4; ++r)
                xr[r] = *(const float4*)&LB[WB1_O + (pr0+r)*64 + k4*4];  // own rows
            #pragma unroll
            for (int kk = 0; kk < 4; ++kk) {
                v2f w = ((const v2f*)(pw2 + (k4*4+kk)*128))[lane];
                #pragma unroll
                for (int r = 0; r < 4; ++r) {
                    float xv = ((const float*)&xr[r])[kk];
                    acc[r] += w * xv;
                }
            }
        }
        #pragma unroll
        for (int r = 0; r < 4; ++r) {
            float2 o; o.x = acc[r].x + bv.x; o.y = acc[r].y + bv.y;
            ((float2*)(X0 + (size_t)(pr0 + r)*128))[lane] = o;
        }
    }

    #pragma unroll 1
    for (int l = 0; l < 4; ++l) {
        const float* Xl  = XbR + ((size_t)l*NR + b*TW) * 128;
        float*       Xo  = XbW + ((size_t)(l+1)*NR + b*TW) * 128;
        const float* W1l = fc1w + (size_t)l * 32768;
        const float* W1n = fc1w + (size_t)(l < 3 ? l+1 : l) * 32768;
        const float* W2g = fc2w + (size_t)l * 32768;
        const int rbg = __builtin_amdgcn_readfirstlane(row0);
        const float* x0 = Xl + (size_t)rbg * 128;           // uniform base

        // ---- fc1: compute waves CONSUME, helper waves stage ---------------
        // entry invariant: WB0 = s0(l), helper regs = s1(l) in flight
        v2f accA[8], accB[8];
        #pragma unroll
        for (int r = 0; r < 8; ++r) {
            accA[r].x = 0.f; accA[r].y = 0.f;
            accB[r].x = 0.f; accB[r].y = 0.f;
        }
        __syncthreads();
        if (wave >= 8) { WRITEQ(WB1_O); LOADQ(W1l + 16384); } else CONSUME(WB0_O, 0);
        __syncthreads();
        if (wave >= 8) { WRITEQ(WB0_O); LOADQ(W1l + 24576); } else CONSUME(WB1_O, 32);
        __syncthreads();
        if (wave >= 8) { WRITEQ(WB1_O); LOADQ(W1n);         } else CONSUME(WB0_O, 64);
        __syncthreads();
        if (wave >= 8) { WRITEQ(WB0_O); LOADQ(W1n + 8192);  } else CONSUME(WB1_O, 96);
        // exit invariant: WB0 = s0(l+1), helper regs = s1(l+1) in flight

        if (wave < 8) {
            // ---- LN1 (same tree/order) ----
            {
                float4 b1v = ((const float4*)(fc1b + l*256))[lane];
                float4 g1v = ((const float4*)(n1g  + l*256))[lane];
                float4 t1v = ((const float4*)(n1b  + l*256))[lane];
                #pragma unroll
                for (int r = 0; r < 8; ++r) {
                    float a0 = accA[r].x + b1v.x, a1 = accA[r].y + b1v.y;
                    float a2 = accB[r].x + b1v.z, a3 = accB[r].y + b1v.w;
                    float s = a0 + a1 + a2 + a3;
                    #pragma unroll
                    for (int m = 1; m < 64; m <<= 1) s += __shfl_xor(s, m, 64);
                    float mean = s * (1.0f/256.0f);
                    float dx = a0-mean, dy = a1-mean, dz = a2-mean, dw = a3-mean;
                    float q2 = dx*dx + dy*dy + dz*dz + dw*dw;
                    #pragma unroll
                    for (int m = 1; m < 64; m <<= 1) q2 += __shfl_xor(q2, m, 64);
                    float inv = 1.0f / sqrtf(q2 * (1.0f/256.0f) + 1e-5f);
                    accA[r].x = dx*inv*g1v.x + t1v.x; accA[r].y = dy*inv*g1v.y + t1v.y;
                    accB[r].x = dz*inv*g1v.z + t1v.z; accB[r].y = dw*inv*g1v.w + t1v.w;
                }
            }
            // ---- LIF1: 8-stage flag chain; masks -> wave-private LDS -------
            {
                const int tgt = l*8 + wave;
                while (__hip_atomic_load(&FLG[0], __ATOMIC_ACQUIRE,
                                         __HIP_MEMORY_SCOPE_WORKGROUP) < tgt)
                    __builtin_amdgcn_s_sleep(1);
                float v0, v1, v2, v3;
                if (wave == 0) { v0 = v1 = v2 = v3 = 0.f; }
                else { float4 vv = *(const float4*)&LB[V1_O + lane*4];
                       v0 = vv.x; v1 = vv.y; v2 = vv.z; v3 = vv.w; }
                #pragma unroll
                for (int i = 0; i < 8; ++i) {
                    v0 += (accA[i].x - v0) * 0.5f;
                    v1 += (accA[i].y - v1) * 0.5f;
                    v2 += (accB[i].x - v2) * 0.5f;
                    v3 += (accB[i].y - v3) * 0.5f;
                    bool s0 = v0 >= 1.f, s1 = v1 >= 1.f, s2 = v2 >= 1.f, s3 = v3 >= 1.f;
                    unsigned long long b0 = __ballot(s0), b1 = __ballot(s1);
                    unsigned long long b2 = __ballot(s2), b3 = __ballot(s3);
                    if (lane == 0) {
                        unsigned long long* mp = MSK + (size_t)(wave*8 + i)*4;
                        mp[0] = b0; mp[1] = b1; mp[2] = b2; mp[3] = b3;
                    }
                    v0 = s0 ? 0.f : v0;  v1 = s1 ? 0.f : v1;
                    v2 = s2 ? 0.f : v2;  v3 = s3 ? 0.f : v3;
                }
                float4 vv; vv.x = v0; vv.y = v1; vv.z = v2; vv.w = v3;
                *(float4*)&LB[V1_O + lane*4] = vv;
                if (lane == 0)
                    __hip_atomic_store(&FLG[0], tgt+1, __ATOMIC_RELEASE,
                                       __HIP_MEMORY_SCOPE_WORKGROUP);
            }
            // ---- fc2 sparse: d-ascending exact-zero adds, depth-1 pipeline -
            float a2x[8], a2y[8];
            #pragma unroll
            for (int i = 0; i < 8; ++i) {
                const unsigned long long* mp = MSK + (size_t)(wave*8 + i)*4;
                unsigned long long m0 = rfl64(mp[0]);
                unsigned long long m1 = rfl64(mp[1]);
                unsigned long long m2 = rfl64(mp[2]);
                unsigned long long m3 = rfl64(mp[3]);
                unsigned long long mm = m0 | m1 | m2 | m3;
                float ax = 0.f, ay = 0.f;
                if (mm) {
                    int id = __builtin_ctzll(mm); mm &= mm - 1;
                    const float* wr = W2g + (size_t)id * 512;
                    float2 w0 = ((const float2*)(wr      ))[lane];
                    float2 w1 = ((const float2*)(wr + 128))[lane];
                    float2 w2 = ((const float2*)(wr + 256))[lane];
                    float2 w3 = ((const float2*)(wr + 384))[lane];
                    unsigned long long bit = 1ull << id;
                    while (mm) {
                        int id2 = __builtin_ctzll(mm); mm &= mm - 1;
                        const float* wr2 = W2g + (size_t)id2 * 512;
                        float2 n0 = ((const float2*)(wr2      ))[lane];
                        float2 n1 = ((const float2*)(wr2 + 128))[lane];
                        float2 n2 = ((const float2*)(wr2 + 256))[lane];
                        float2 n3 = ((const float2*)(wr2 + 384))[lane];
                        ax += (m0 & bit) ? w0.x : 0.f;  ay += (m0 & bit) ? w0.y : 0.f;
                        ax += (m1 & bit) ? w1.x : 0.f;  ay += (m1 & bit) ? w1.y : 0.f;
                        ax += (m2 & bit) ? w2.x : 0.f;  ay += (m2 & bit) ? w2.y : 0.f;
                        ax += (m3 & bit) ? w3.x : 0.f;  ay += (m3 & bit) ? w3.y : 0.f;
                        bit = 1ull << id2;
                        w0 = n0; w1 = n1; w2 = n2; w3 = n3;
                    }
                    ax += (m0 & bit) ? w0.x : 0.f;  ay += (m0 & bit) ? w0.y : 0.f;
                    ax += (m1 & bit) ? w1.x : 0.f;  ay += (m1 & bit) ? w1.y : 0.f;
                    ax += (m2 & bit) ? w2.x : 0.f;  ay += (m2 & bit) ? w2.y : 0.f;
                    ax += (m3 & bit) ? w3.x : 0.f;  ay += (m3 & bit) ? w3.y : 0.f;
                }
                a2x[i] = ax; a2y[i] = ay;
            }
            // ---- LN2 (same tree/order) ----
            {
                float2 b2v = ((const float2*)(fc2b + l*128))[lane];
                float2 g2v = ((const float2*)(n2g  + l*128))[lane];
                float2 t2v = ((const float2*)(n2b  + l*128))[lane];
                #pragma unroll
                for (int i = 0; i < 8; ++i) {
                    float ax = a2x[i] + b2v.x, ay = a2y[i] + b2v.y;
                    float s = ax + ay;
                    #pragma unroll
                    for (int m = 1; m < 64; m <<= 1) s += __shfl_xor(s, m, 64);
                    float mean = s * (1.0f/128.0f);
                    float dx = ax - mean, dy = ay - mean;
                    float q = dx*dx + dy*dy;
                    #pragma unroll
                    for (int m = 1; m < 64; m <<= 1) q += __shfl_xor(q, m, 64);
                    float inv = 1.0f / sqrtf(q * (1.0f/128.0f) + 1e-5f);
                    a2x[i] = dx*inv*g2v.x + t2v.x;
                    a2y[i] = dy*inv*g2v.y + t2v.y;
                }
            }
            // ---- LIF2 + residual: 8-stage chain; X(l) -> X(l+1) global -----
            {
                const int tgt = l*8 + wave;
                while (__hip_atomic_load(&FLG[1], __ATOMIC_ACQUIRE,
                                         __HIP_MEMORY_SCOPE_WORKGROUP) < tgt)
                    __builtin_amdgcn_s_sleep(1);
                float u0, u1;
                if (wave == 0) { u0 = u1 = 0.f; }
                else { float2 uv = *(const float2*)&LB[V2_O + lane*2];
                       u0 = uv.x; u1 = uv.y; }
                #pragma unroll
                for (int i = 0; i < 8; ++i) {
                    int t = row0 + i;
                    u0 += (a2x[i] - u0) * 0.5f;
                    u1 += (a2y[i] - u1) * 0.5f;
                    bool s0 = u0 >= 1.f, s1 = u1 >= 1.f;
                    float2 xv = ((const float2*)(Xl + (size_t)t*128))[lane];
                    float2 xn;
                    xn.x = xv.x + (s0 ? 1.f : 0.f);
                    xn.y = xv.y + (s1 ? 1.f : 0.f);
                    ((float2*)(Xo + (size_t)t*128))[lane] = xn;
                    u0 = s0 ? 0.f : u0;
                    u1 = s1 ? 0.f : u1;
                    if (l == 3 && t == 63)
                        ((float2*)(out + b*128))[lane] = xn;     // row t=2047
                }
                float2 uv; uv.x = u0; uv.y = u1;
                *(float2*)&LB[V2_O + lane*2] = uv;
                if (lane == 0)
                    __hip_atomic_store(&FLG[1], tgt+1, __ATOMIC_RELEASE,
                                       __HIP_MEMORY_SCOPE_WORKGROUP);
            }
        }
        // next layer's first __syncthreads orders Xo stores before s_loads
    }
#undef LOADQ
#undef WRITEQ
#undef CONSUME
}

extern "C" void kernel_launch(void* const* d_in, const int* in_sizes, int n_in,
                              void* d_out, int out_size, void* d_ws, size_t ws_size,
                              hipStream_t stream) {
    const float* hist = (const float*)d_in[0];
    const float* pw1  = (const float*)d_in[1];
    const float* pb1  = (const float*)d_in[2];
    const float* pw2  = (const float*)d_in[3];
    const float* pb2  = (const float*)d_in[4];
    const float* fc1w = (const float*)d_in[5];
    const float* fc1b = (const float*)d_in[6];
    const float* n1g  = (const float*)d_in[7];
    const float* n1b  = (const float*)d_in[8];
    const float* fc2w = (const float*)d_in[9];
    const float* fc2b = (const float*)d_in[10];
    const float* n2g  = (const float*)d_in[11];
    const float* n2b  = (const float*)d_in[12];
    float* out = (float*)d_out;

    float* Xb = (float*)d_ws;        // 5 regions x [NR,128] f32 = 10 MiB

    fused_kernel<<<64, 1024, 0, stream>>>(hist, pw1, pb1, pw2, pb2,
                                          fc1w, fc1b, n1g, n1b,
                                          fc2w, fc2b, n2g, n2b,
                                          (const float*)Xb, Xb, out);
}

// Round 8
// 198.269 us; speedup vs baseline: 1.4385x; 1.4385x over previous
//
#include <hip/hip_runtime.h>
#include <math.h>

// Problem constants
#define NB   64
#define TT   2048
// Tail-window truncation: output = x[:, 2047]; the only temporal coupling is
// the LIF membrane (decay 0.5/step + hard reset). v(T0)=0 direct error at
// 2047 is 0.5^63; validated in prior rounds (TW=192 matched full scan).
#define TW   64
#define T0   (TT - TW)     // 1984
#define NR   (NB * TW)     // 4096 active rows

typedef float v2f __attribute__((ext_vector_type(2)));

__device__ __forceinline__ float gelu_exact(float x) {
    return 0.5f * x * (1.0f + erff(x * 0.7071067811865476f));
}
__device__ __forceinline__ unsigned long long rfl64(unsigned long long x) {
    unsigned lo = __builtin_amdgcn_readfirstlane((unsigned)x);
    unsigned hi = __builtin_amdgcn_readfirstlane((unsigned)(x >> 32));
    return ((unsigned long long)hi << 32) | lo;
}

// LDS float offsets (82.5 KB)
#define XT_O   0        // [32][128] X tile — resident for all layers (16 KB)
#define WB0_O  4096     // [32][256] fc1-W quarter buffer 0 (32 KB)
#define WB1_O  12288    // quarter buffer 1; proj G[32][64] aliases here
#define V1_O   20480    // LIF1 v-state intra-block handoff (256 f)
#define V2_O   20736    // LIF2 v-state intra-block handoff (128 f)
#define MSK_O  20864    // spike masks: [8 waves][4 t][4] u64 = 256 f
#define LB_TOT 21120

// 128 blocks = 64 batches x 2 window-halves (bid = half*64 + b, so a batch's
// two blocks share an XCD slot -- perf heuristic; correctness uses agent
// scope). Block (b,half) owns rows t_local in [0,32) == t = half*32 + t_local.
// 512 threads = 8 waves x 4 rows. Halving waves/CU halves the W-LDS re-read
// traffic (the round-6 bottleneck); halving rows/CU halves the X-broadcast
// reads. X lives in LDS (wave-private rows, zero global round-trips).
// The ONLY cross-block dependency is the LIF membrane state at the t=32
// boundary: half 0's last wave writes v (256/128 floats) to a per-layer
// global buffer and releases a flag; half 1's first wave acquire-spins and
// seeds its chain from it. All accumulation orders are unchanged from the
// verified rounds (k-order, a0+a1+a2+a3 + xor-tree LN, d-ascending sparse
// fc2 with exact-zero adds) -> bit-identical output.
__global__ void __launch_bounds__(512) fused_kernel(
    const float* __restrict__ hist,
    const float* __restrict__ pw1, const float* __restrict__ pb1,
    const float* __restrict__ pw2, const float* __restrict__ pb2,
    const float* __restrict__ fc1w, const float* __restrict__ fc1b,
    const float* __restrict__ n1g,  const float* __restrict__ n1b,
    const float* __restrict__ fc2w, const float* __restrict__ fc2b,
    const float* __restrict__ n2g,  const float* __restrict__ n2b,
    float* __restrict__ v1buf, float* __restrict__ v2buf,
    int* __restrict__ flg1, int* __restrict__ flg2,
    float* __restrict__ out)
{
    __shared__ __align__(16) float LB[LB_TOT];
    __shared__ int FLG[2];
    unsigned long long* MSK = (unsigned long long*)&LB[MSK_O];
    const int tid = threadIdx.x, wave = tid >> 6, lane = tid & 63;
    const int b = blockIdx.x & 63, half = blockIdx.x >> 6;
    const int row0 = wave * 4;           // block-local rows owned by this wave

    if (tid == 0) { FLG[0] = 0; FLG[1] = 0; }

    float4 ra, rb, rc, rd;   // staging regs: 64B/thread = one 32KB quarter
#define LOADQ(src) { const float4* p_ = (const float4*)(src); \
                     ra = p_[tid]; rb = p_[tid+512]; rc = p_[tid+1024]; rd = p_[tid+1536]; }
#define WRITEQ(off) { float4* q_ = (float4*)&LB[off]; \
                      q_[tid] = ra; q_[tid+512] = rb; q_[tid+1024] = rc; q_[tid+1536] = rd; }
#define CONSUME(WOFF, KQ) \
    { \
        _Pragma("unroll 2") \
        for (int k4 = 0; k4 < 8; ++k4) { \
            float4 xr[4]; \
            _Pragma("unroll") \
            for (int r = 0; r < 4; ++r) \
                xr[r] = *(const float4*)&LB[XT_O + (row0+r)*128 + (KQ) + k4*4]; \
            _Pragma("unroll") \
            for (int kk = 0; kk < 4; ++kk) { \
                float4 wv = ((const float4*)&LB[(WOFF) + (k4*4+kk)*256])[lane]; \
                v2f wA, wB; wA.x = wv.x; wA.y = wv.y; wB.x = wv.z; wB.y = wv.w; \
                _Pragma("unroll") \
                for (int r = 0; r < 4; ++r) { \
                    float xv = ((const float*)&xr[r])[kk]; \
                    accA[r] += wA * xv; \
                    accB[r] += wB * xv; \
                } \
            } \
        } \
    }

    LOADQ(fc1w);                               // s0(L0) in flight

    // ---------------- proj1: G = gelu(hist @ pw1 + pb1), wave-local rows ----
    {
        const float* hb = hist + ((size_t)b * TT + T0 + half*32) * 4;
        float w0 = pw1[lane], w1 = pw1[64+lane], w2 = pw1[128+lane], w3 = pw1[192+lane];
        float bb = pb1[lane];
        #pragma unroll
        for (int r = 0; r < 4; ++r) {
            int t = row0 + r;
            float4 h = *(const float4*)(hb + t*4);          // wave-uniform
            LB[WB1_O + t*64 + lane] = gelu_exact(bb + h.x*w0 + h.y*w1 + h.z*w2 + h.w*w3);
        }
    }
    WRITEQ(WB0_O);                             // s0 -> B0 (waits its loads)
    LOADQ(fc1w + 8192);                        // s1(L0) in flight
    // ---------------- proj2: X0 = G @ pw2 + pb2 -> XT (wave-local rows) -----
    {
        float2 bv = ((const float2*)pb2)[lane];
        v2f acc[4];
        #pragma unroll
        for (int r = 0; r < 4; ++r) { acc[r].x = 0.f; acc[r].y = 0.f; }
        #pragma unroll 2
        for (int k4 = 0; k4 < 16; ++k4) {
            float4 xr[4];
            #pragma unroll
            for (int r = 0; r < 4; ++r)
                xr[r] = *(const float4*)&LB[WB1_O + (row0+r)*64 + k4*4];  // own rows
            #pragma unroll
            for (int kk = 0; kk < 4; ++kk) {
                v2f w = ((const v2f*)(pw2 + (k4*4+kk)*128))[lane];
                #pragma unroll
                for (int r = 0; r < 4; ++r) {
                    float xv = ((const float*)&xr[r])[kk];
                    acc[r] += w * xv;
                }
            }
        }
        #pragma unroll
        for (int r = 0; r < 4; ++r) {
            float2 o; o.x = acc[r].x + bv.x; o.y = acc[r].y + bv.y;
            *(float2*)&LB[XT_O + (row0+r)*128 + lane*2] = o;
        }
    }

    #pragma unroll 1
    for (int l = 0; l < 4; ++l) {
        const float* W1l = fc1w + (size_t)l * 32768;
        const float* W1n = fc1w + (size_t)(l < 3 ? l+1 : l) * 32768;
        const float* W2g = fc2w + (size_t)l * 32768;

        // ---- fc1: H = X @ W1, K quartered, double-buffered LDS W ----------
        // entry invariant: WB0 = s0(l) written, regs = s1(l) in flight
        v2f accA[4], accB[4];
        #pragma unroll
        for (int r = 0; r < 4; ++r) {
            accA[r].x = 0.f; accA[r].y = 0.f;
            accB[r].x = 0.f; accB[r].y = 0.f;
        }
        __syncthreads(); WRITEQ(WB1_O); LOADQ(W1l + 16384); CONSUME(WB0_O, 0);
        __syncthreads(); WRITEQ(WB0_O); LOADQ(W1l + 24576); CONSUME(WB1_O, 32);
        __syncthreads(); WRITEQ(WB1_O); LOADQ(W1n);         CONSUME(WB0_O, 64);
        __syncthreads(); WRITEQ(WB0_O); LOADQ(W1n + 8192);  CONSUME(WB1_O, 96);
        // exit invariant: WB0 = s0(l+1), regs = s1(l+1) in flight

        // ---- LN1 (same tree/order) ----
        {
            float4 b1v = ((const float4*)(fc1b + l*256))[lane];
            float4 g1v = ((const float4*)(n1g  + l*256))[lane];
            float4 t1v = ((const float4*)(n1b  + l*256))[lane];
            #pragma unroll
            for (int r = 0; r < 4; ++r) {
                float a0 = accA[r].x + b1v.x, a1 = accA[r].y + b1v.y;
                float a2 = accB[r].x + b1v.z, a3 = accB[r].y + b1v.w;
                float s = a0 + a1 + a2 + a3;
                #pragma unroll
                for (int m = 1; m < 64; m <<= 1) s += __shfl_xor(s, m, 64);
                float mean = s * (1.0f/256.0f);
                float dx = a0-mean, dy = a1-mean, dz = a2-mean, dw = a3-mean;
                float q2 = dx*dx + dy*dy + dz*dz + dw*dw;
                #pragma unroll
                for (int m = 1; m < 64; m <<= 1) q2 += __shfl_xor(q2, m, 64);
                float inv = 1.0f / sqrtf(q2 * (1.0f/256.0f) + 1e-5f);
                accA[r].x = dx*inv*g1v.x + t1v.x; accA[r].y = dy*inv*g1v.y + t1v.y;
                accB[r].x = dz*inv*g1v.z + t1v.z; accB[r].y = dw*inv*g1v.w + t1v.w;
            }
        }
        // ---- LIF1: 8-stage intra-block flag chain; cross-block seed/emit ---
        {
            const int tgt = l*8 + wave;
            while (__hip_atomic_load(&FLG[0], __ATOMIC_ACQUIRE,
                                     __HIP_MEMORY_SCOPE_WORKGROUP) < tgt)
                __builtin_amdgcn_s_sleep(1);
            float v0, v1, v2, v3;
            if (wave == 0) {
                if (half == 0) { v0 = v1 = v2 = v3 = 0.f; }
                else {
                    while (__hip_atomic_load(&flg1[b], __ATOMIC_RELAXED,
                                             __HIP_MEMORY_SCOPE_AGENT) < l+1)
                        __builtin_amdgcn_s_sleep(1);
                    __builtin_amdgcn_fence(__ATOMIC_ACQUIRE, "agent");
                    float4 vv = *(const float4*)&v1buf[(size_t)l*NB*256 + b*256 + lane*4];
                    v0 = vv.x; v1 = vv.y; v2 = vv.z; v3 = vv.w;
                }
            } else {
                float4 vv = *(const float4*)&LB[V1_O + lane*4];
                v0 = vv.x; v1 = vv.y; v2 = vv.z; v3 = vv.w;
            }
            #pragma unroll
            for (int i = 0; i < 4; ++i) {
                v0 += (accA[i].x - v0) * 0.5f;
                v1 += (accA[i].y - v1) * 0.5f;
                v2 += (accB[i].x - v2) * 0.5f;
                v3 += (accB[i].y - v3) * 0.5f;
                bool s0 = v0 >= 1.f, s1 = v1 >= 1.f, s2 = v2 >= 1.f, s3 = v3 >= 1.f;
                unsigned long long b0 = __ballot(s0), b1 = __ballot(s1);
                unsigned long long b2 = __ballot(s2), b3 = __ballot(s3);
                if (lane == 0) {
                    unsigned long long* mp = MSK + (size_t)(wave*4 + i)*4;
                    mp[0] = b0; mp[1] = b1; mp[2] = b2; mp[3] = b3;
                }
                v0 = s0 ? 0.f : v0;  v1 = s1 ? 0.f : v1;
                v2 = s2 ? 0.f : v2;  v3 = s3 ? 0.f : v3;
            }
            if (wave < 7) {
                float4 vv; vv.x = v0; vv.y = v1; vv.z = v2; vv.w = v3;
                *(float4*)&LB[V1_O + lane*4] = vv;
            } else if (half == 0) {
                float4 vv; vv.x = v0; vv.y = v1; vv.z = v2; vv.w = v3;
                *(float4*)&v1buf[(size_t)l*NB*256 + b*256 + lane*4] = vv;
                __builtin_amdgcn_fence(__ATOMIC_RELEASE, "agent");
                if (lane == 0)
                    __hip_atomic_store(&flg1[b], l+1, __ATOMIC_RELAXED,
                                       __HIP_MEMORY_SCOPE_AGENT);
            }
            if (lane == 0)
                __hip_atomic_store(&FLG[0], tgt+1, __ATOMIC_RELEASE,
                                   __HIP_MEMORY_SCOPE_WORKGROUP);
        }
        // ---- fc2 sparse: d-ascending exact-zero adds, depth-1 pipelined ----
        float a2x[4], a2y[4];
        #pragma unroll
        for (int i = 0; i < 4; ++i) {
            const unsigned long long* mp = MSK + (size_t)(wave*4 + i)*4;
            unsigned long long m0 = rfl64(mp[0]);
            unsigned long long m1 = rfl64(mp[1]);
            unsigned long long m2 = rfl64(mp[2]);
            unsigned long long m3 = rfl64(mp[3]);
            unsigned long long mm = m0 | m1 | m2 | m3;
            float ax = 0.f, ay = 0.f;
            if (mm) {
                int id = __builtin_ctzll(mm); mm &= mm - 1;
                const float* wr = W2g + (size_t)id * 512;
                float2 w0 = ((const float2*)(wr      ))[lane];
                float2 w1 = ((const float2*)(wr + 128))[lane];
                float2 w2 = ((const float2*)(wr + 256))[lane];
                float2 w3 = ((const float2*)(wr + 384))[lane];
                unsigned long long bit = 1ull << id;
                while (mm) {
                    int id2 = __builtin_ctzll(mm); mm &= mm - 1;
                    const float* wr2 = W2g + (size_t)id2 * 512;
                    float2 n0 = ((const float2*)(wr2      ))[lane];
                    float2 n1 = ((const float2*)(wr2 + 128))[lane];
                    float2 n2 = ((const float2*)(wr2 + 256))[lane];
                    float2 n3 = ((const float2*)(wr2 + 384))[lane];
                    ax += (m0 & bit) ? w0.x : 0.f;  ay += (m0 & bit) ? w0.y : 0.f;
                    ax += (m1 & bit) ? w1.x : 0.f;  ay += (m1 & bit) ? w1.y : 0.f;
                    ax += (m2 & bit) ? w2.x : 0.f;  ay += (m2 & bit) ? w2.y : 0.f;
                    ax += (m3 & bit) ? w3.x : 0.f;  ay += (m3 & bit) ? w3.y : 0.f;
                    bit = 1ull << id2;
                    w0 = n0; w1 = n1; w2 = n2; w3 = n3;
                }
                ax += (m0 & bit) ? w0.x : 0.f;  ay += (m0 & bit) ? w0.y : 0.f;
                ax += (m1 & bit) ? w1.x : 0.f;  ay += (m1 & bit) ? w1.y : 0.f;
                ax += (m2 & bit) ? w2.x : 0.f;  ay += (m2 & bit) ? w2.y : 0.f;
                ax += (m3 & bit) ? w3.x : 0.f;  ay += (m3 & bit) ? w3.y : 0.f;
            }
            a2x[i] = ax; a2y[i] = ay;
        }
        // ---- LN2 (same tree/order) ----
        {
            float2 b2v = ((const float2*)(fc2b + l*128))[lane];
            float2 g2v = ((const float2*)(n2g  + l*128))[lane];
            float2 t2v = ((const float2*)(n2b  + l*128))[lane];
            #pragma unroll
            for (int i = 0; i < 4; ++i) {
                float ax = a2x[i] + b2v.x, ay = a2y[i] + b2v.y;
                float s = ax + ay;
                #pragma unroll
                for (int m = 1; m < 64; m <<= 1) s += __shfl_xor(s, m, 64);
                float mean = s * (1.0f/128.0f);
                float dx = ax - mean, dy = ay - mean;
                float q = dx*dx + dy*dy;
                #pragma unroll
                for (int m = 1; m < 64; m <<= 1) q += __shfl_xor(q, m, 64);
                float inv = 1.0f / sqrtf(q * (1.0f/128.0f) + 1e-5f);
                a2x[i] = dx*inv*g2v.x + t2v.x;
                a2y[i] = dy*inv*g2v.y + t2v.y;
            }
        }
        // ---- LIF2 + residual on LDS X tile; cross-block seed/emit ----------
        {
            const int tgt = l*8 + wave;
            while (__hip_atomic_load(&FLG[1], __ATOMIC_ACQUIRE,
                                     __HIP_MEMORY_SCOPE_WORKGROUP) < tgt)
                __builtin_amdgcn_s_sleep(1);
            float u0, u1;
            if (wave == 0) {
                if (half == 0) { u0 = u1 = 0.f; }
                else {
                    while (__hip_atomic_load(&flg2[b], __ATOMIC_RELAXED,
                                             __HIP_MEMORY_SCOPE_AGENT) < l+1)
                        __builtin_amdgcn_s_sleep(1);
                    __builtin_amdgcn_fence(__ATOMIC_ACQUIRE, "agent");
                    float2 uv = *(const float2*)&v2buf[(size_t)l*NB*128 + b*128 + lane*2];
                    u0 = uv.x; u1 = uv.y;
                }
            } else {
                float2 uv = *(const float2*)&LB[V2_O + lane*2];
                u0 = uv.x; u1 = uv.y;
            }
            #pragma unroll
            for (int i = 0; i < 4; ++i) {
                int t = row0 + i;
                u0 += (a2x[i] - u0) * 0.5f;
                u1 += (a2y[i] - u1) * 0.5f;
                bool s0 = u0 >= 1.f, s1 = u1 >= 1.f;
                float2 xv = *(const float2*)&LB[XT_O + t*128 + lane*2];
                float2 xn;
                xn.x = xv.x + (s0 ? 1.f : 0.f);
                xn.y = xv.y + (s1 ? 1.f : 0.f);
                *(float2*)&LB[XT_O + t*128 + lane*2] = xn;
                u0 = s0 ? 0.f : u0;
                u1 = s1 ? 0.f : u1;
                if (l == 3 && half == 1 && t == 31)
                    ((float2*)(out + b*128))[lane] = xn;     // row t=2047
            }
            if (wave < 7) {
                float2 uv; uv.x = u0; uv.y = u1;
                *(float2*)&LB[V2_O + lane*2] = uv;
            } else if (half == 0) {
                float2 uv; uv.x = u0; uv.y = u1;
                *(float2*)&v2buf[(size_t)l*NB*128 + b*128 + lane*2] = uv;
                __builtin_amdgcn_fence(__ATOMIC_RELEASE, "agent");
                if (lane == 0)
                    __hip_atomic_store(&flg2[b], l+1, __ATOMIC_RELAXED,
                                       __HIP_MEMORY_SCOPE_AGENT);
            }
            if (lane == 0)
                __hip_atomic_store(&FLG[1], tgt+1, __ATOMIC_RELEASE,
                                   __HIP_MEMORY_SCOPE_WORKGROUP);
        }
    }
#undef LOADQ
#undef WRITEQ
#undef CONSUME
}

extern "C" void kernel_launch(void* const* d_in, const int* in_sizes, int n_in,
                              void* d_out, int out_size, void* d_ws, size_t ws_size,
                              hipStream_t stream) {
    const float* hist = (const float*)d_in[0];
    const float* pw1  = (const float*)d_in[1];
    const float* pb1  = (const float*)d_in[2];
    const float* pw2  = (const float*)d_in[3];
    const float* pb2  = (const float*)d_in[4];
    const float* fc1w = (const float*)d_in[5];
    const float* fc1b = (const float*)d_in[6];
    const float* n1g  = (const float*)d_in[7];
    const float* n1b  = (const float*)d_in[8];
    const float* fc2w = (const float*)d_in[9];
    const float* fc2b = (const float*)d_in[10];
    const float* n2g  = (const float*)d_in[11];
    const float* n2b  = (const float*)d_in[12];
    float* out = (float*)d_out;

    char* ws = (char*)d_ws;
    float* v1buf = (float*)ws;                      // [4][64][256] = 256 KB
    float* v2buf = (float*)(ws + (1ull << 20));     // [4][64][128] = 128 KB
    int*   flg1  = (int*)(ws + (2ull << 20));       // [64]
    int*   flg2  = flg1 + 64;

    hipMemsetAsync(flg1, 0, 128 * sizeof(int), stream);
    fused_kernel<<<128, 512, 0, stream>>>(hist, pw1, pb1, pw2, pb2,
                                          fc1w, fc1b, n1g, n1b,
                                          fc2w, fc2b, n2g, n2b,
                                          v1buf, v2buf, flg1, flg2, out);
}